// Round 7
// baseline (127.779 us; speedup 1.0000x reference)
//
#include <hip/hip_runtime.h>
#include <hip/hip_bf16.h>

#define BATCH 4096
#define NROWS 8192
#define DIM   128
#define NTILE 64

typedef __bf16 bf16x8 __attribute__((ext_vector_type(8)));
typedef __bf16 bf16x2 __attribute__((ext_vector_type(2)));
typedef float  f32x4  __attribute__((ext_vector_type(4)));

// ---------------------------------------------------------------------------
// Kernel 1: row-normalize z = concat(zx, zy) -> bf16 zn [8192 x 128].
// One wave per row. Also zero-initializes S (blocks 0..31) and out (block 0)
// so later dispatches accumulate into poisoned workspace with no memsets.
// ---------------------------------------------------------------------------
__global__ __launch_bounds__(256) void normalize_kernel(
    const float* __restrict__ zx, const float* __restrict__ zy,
    ushort* __restrict__ zn, float* __restrict__ S, float* __restrict__ out)
{
  const int tid  = threadIdx.x;
  const int lane = tid & 63;
  const int w    = tid >> 6;
  const int row  = blockIdx.x * 4 + w;
  if (blockIdx.x < 32) S[blockIdx.x * 256 + tid] = 0.f;
  if (blockIdx.x == 0 && tid == 0) out[0] = 0.f;
  const float* src = (row < BATCH) ? (zx + (size_t)row * DIM)
                                   : (zy + (size_t)(row - BATCH) * DIM);
  float2 v = ((const float2*)src)[lane];
  float ss = v.x * v.x + v.y * v.y;
#pragma unroll
  for (int off = 1; off < 64; off <<= 1)
    ss += __shfl_xor(ss, off, 64);
  float inv = 1.0f / fmaxf(sqrtf(ss), 1e-8f);
  bf16x2 st;
  st.x = (__bf16)(v.x * inv);
  st.y = (__bf16)(v.y * inv);
  reinterpret_cast<bf16x2*>(zn + (size_t)row * DIM)[lane] = st;
}

// ---------------------------------------------------------------------------
// Kernel 2 (v7): LDS-FREE symmetry-halved sim/exp-sum.
// Round-6 counters showed the staged version ~85% stalled (MfmaUtil 5%,
// VALUBusy 10%, occupancy 16%): latency-bound, not throughput-bound. zn is
// 2 MiB = L2-resident, so LDS staging bought nothing and cost 64 KiB LDS
// (occupancy cap) + 2 barriers/tile (serialization). v7 loads B-fragments
// straight from L2 per wave (same 16-rows x 64B pattern as the A-frag loads),
// has ZERO __syncthreads and ZERO LDS, and runs 1024 blocks at 3 blocks/CU
// (launch_bounds(256,3), VGPR cap ~170) = 12 fully independent waves/CU.
//
// Work decomposition: lower triangle (2080 tiles of 128x128) as 32 row-pairs
// {p, 63-p} of 65 tiles each, split into 32 chunks (chunk 0: 3 tiles, rest 2;
// contiguous, so at most one A-frag reload per block at the row switch).
// Per tile: exp values feed row-block sums (held in registers across the row
// run) and col-block sums (flushed per tile); both land in S[8192] via
// shfl-reduce + atomicAdd (S pre-zeroed). Positive-pair tiles (rb-cb==32)
// write P[i] and mirror P[i-4096] (sim is symmetric).
// ---------------------------------------------------------------------------
__global__ __launch_bounds__(256, 3) void simloss_kernel(
    const ushort* __restrict__ zn, float* __restrict__ S,
    float* __restrict__ P)
{
  const int tid  = threadIdx.x;
  const int lane = tid & 63;
  const int w    = tid >> 6;
  const int wr   = w >> 1, wc = w & 1;
  const int q    = lane >> 4;     // quad 0..3
  const int l15  = lane & 15;

  const int p  = blockIdx.x >> 5;            // pair 0..31: rows {p, 63-p}
  const int ch = blockIdx.x & 31;            // chunk 0..31
  const int o0 = (ch == 0) ? 0 : 1 + ch * 2; // seq start: 0,3,5,...,63
  const int T  = (ch == 0) ? 3 : 2;          // tiles in this chunk
  const int L0 = p + 1;                      // tiles in short row (rb = p)

  // seq position o -> tile (rb, cb); row p then row 63-p, cb ascending.
  auto tile_rc = [&](int o, int& rb, int& cb) {
    if (o < L0) { rb = p;      cb = o; }
    else        { rb = 63 - p; cb = o - L0; }
  };

  // A fragments: rows rb*128 + wr*64 + mi*16 + l15, k chunk q*8 within ks*32
  bf16x8 af[4][4];
  auto loadA = [&](int rb) {
    const int arow = rb * 128 + wr * 64 + l15;
#pragma unroll
    for (int mi = 0; mi < 4; ++mi)
#pragma unroll
      for (int ks = 0; ks < 4; ++ks) {
        const ushort* ap = zn + (size_t)(arow + mi * 16) * DIM + ks * 32 + q * 8;
        af[mi][ks] = *reinterpret_cast<const bf16x8*>(ap);
      }
  };

  int rb0, cb0;
  tile_rc(o0, rb0, cb0);
  loadA(rb0);

  f32x4 Srow[4];       // per mi, elems r=0..3
#pragma unroll
  for (int mi = 0; mi < 4; ++mi) Srow[mi] = (f32x4){0.f, 0.f, 0.f, 0.f};

  const float K1 = 2.8853900817779268f;  // (1/TEMP) * log2(e)

  for (int t = 0; t < T; ++t) {
    const int o = o0 + t;
    int trb, tcb;
    tile_rc(o, trb, tcb);
    int nrb = -1, ncb = -1;
    if (t + 1 < T) tile_rc(o + 1, nrb, ncb);

    f32x4 acc[4][4];
#pragma unroll
    for (int mi = 0; mi < 4; ++mi)
#pragma unroll
      for (int ni = 0; ni < 4; ++ni)
        acc[mi][ni] = (f32x4){0.f, 0.f, 0.f, 0.f};

    // B-fragments straight from zn (L2-resident): row nl of col-block tcb,
    // 16B per lane; a wave touches 16 rows x 64B contiguous per (ks,ni).
    const ushort* bbase = zn + (size_t)(tcb * 128) * DIM;
#pragma unroll
    for (int ks = 0; ks < 4; ++ks) {
      bf16x8 bf[4];
#pragma unroll
      for (int ni = 0; ni < 4; ++ni) {
        const int nl = wc * 64 + ni * 16 + l15;   // B row in tile (sim col)
        bf[ni] = *reinterpret_cast<const bf16x8*>(
            bbase + (size_t)nl * DIM + ks * 32 + q * 8);
      }
#pragma unroll
      for (int mi = 0; mi < 4; ++mi)
#pragma unroll
        for (int ni = 0; ni < 4; ++ni)
          acc[mi][ni] = __builtin_amdgcn_mfma_f32_16x16x32_bf16(
              af[mi][ks], bf[ni], acc[mi][ni], 0, 0, 0);
    }

    // Epilogue: v = exp(sim-2) = exp2(K1*dot - K1). Row sums accumulate
    // across the row run (f32x4 += -> pk_add); col sums flushed per tile.
    const bool diag = (trb == tcb);
    float Scol[4];
#pragma unroll
    for (int ni = 0; ni < 4; ++ni) Scol[ni] = 0.f;

#pragma unroll
    for (int mi = 0; mi < 4; ++mi)
#pragma unroll
      for (int ni = 0; ni < 4; ++ni) {
        f32x4 vv;
#pragma unroll
        for (int r = 0; r < 4; ++r) {
          float d = acc[mi][ni][r];
          float v = __builtin_amdgcn_exp2f(fmaf(d, K1, -K1));
          if (diag) {
            const int rl = wr * 64 + mi * 16 + q * 4 + r;
            const int cl = wc * 64 + ni * 16 + l15;
            if (rl == cl) v = 0.f;
          }
          vv[r] = v;
        }
        Srow[mi] += vv;
        Scol[ni] += (vv[0] + vv[1]) + (vv[2] + vv[3]);
      }

    // Positive pairs: tile (rb, rb-32) has sim[i, i-4096] at local rl==cl.
    if (trb - tcb == 32) {
#pragma unroll
      for (int mi = 0; mi < 4; ++mi) {
        const int rl0 = wr * 64 + mi * 16 + q * 4;
#pragma unroll
        for (int ni = 0; ni < 4; ++ni) {
          const int cl = wc * 64 + ni * 16 + l15;
#pragma unroll
          for (int r = 0; r < 4; ++r) {
            if (cl == rl0 + r) {
              const int gr = trb * 128 + rl0 + r;
              const float pv = 2.0f * acc[mi][ni][r];
              P[gr] = pv;
              P[gr - 4096] = pv;   // symmetric partner
            }
          }
        }
      }
    }

    // Col-side flush (skip on diagonal tiles). Reduce over quads; 16 lanes
    // atomicAdd per ni.
    if (!diag) {
#pragma unroll
      for (int ni = 0; ni < 4; ++ni) {
        float v = Scol[ni];
        v += __shfl_xor(v, 16, 64);
        v += __shfl_xor(v, 32, 64);
        if (lane < 16)
          atomicAdd(&S[tcb * 128 + wc * 64 + ni * 16 + l15], v);
      }
    }

    // Row-side flush at row switch or block end.
    const bool flushR = (t == T - 1) || (nrb != trb);
    if (flushR) {
#pragma unroll
      for (int mi = 0; mi < 4; ++mi)
#pragma unroll
        for (int r = 0; r < 4; ++r) {
          float v = Srow[mi][r];
          v += __shfl_xor(v, 1, 64);
          v += __shfl_xor(v, 2, 64);
          v += __shfl_xor(v, 4, 64);
          v += __shfl_xor(v, 8, 64);
          if (l15 == 0)
            atomicAdd(&S[trb * 128 + wr * 64 + mi * 16 + q * 4 + r], v);
        }
#pragma unroll
      for (int mi = 0; mi < 4; ++mi) Srow[mi] = (f32x4){0.f, 0.f, 0.f, 0.f};
      if (t + 1 < T && nrb != trb) loadA(nrb);  // one-time A reload
    }
  }
}

// ---------------------------------------------------------------------------
// Kernel 3: loss = mean_i( 2 + log(S_i) - P_i ); out zeroed by normalize.
// ---------------------------------------------------------------------------
__global__ __launch_bounds__(256) void finalize_kernel(
    const float* __restrict__ S, const float* __restrict__ P,
    float* __restrict__ out)
{
  const int i = blockIdx.x * 256 + threadIdx.x;
  float c = 2.0f + logf(S[i]) - P[i];
#pragma unroll
  for (int off = 1; off < 64; off <<= 1)
    c += __shfl_xor(c, off, 64);
  __shared__ float wsum[4];
  const int lane = threadIdx.x & 63, w = threadIdx.x >> 6;
  if (lane == 0) wsum[w] = c;
  __syncthreads();
  if (threadIdx.x == 0)
    atomicAdd(out, (wsum[0] + wsum[1] + wsum[2] + wsum[3]) * (1.0f / NROWS));
}

// ---------------------------------------------------------------------------
extern "C" void kernel_launch(void* const* d_in, const int* in_sizes, int n_in,
                              void* d_out, int out_size, void* d_ws, size_t ws_size,
                              hipStream_t stream)
{
  const float* zx = (const float*)d_in[0];
  const float* zy = (const float*)d_in[1];
  ushort* zn = (ushort*)d_ws;                                      // 2 MiB bf16
  float*  P  = (float*)((char*)d_ws + (size_t)NROWS * DIM * 2);    // 32 KiB
  float*  S  = P + NROWS;                                          // 32 KiB
  float*  out = (float*)d_out;

  normalize_kernel<<<NROWS / 4, 256, 0, stream>>>(zx, zy, zn, S, out);
  simloss_kernel<<<1024, 256, 0, stream>>>(zn, S, P);
  finalize_kernel<<<NROWS / 256, 256, 0, stream>>>(S, P, out);
}

// Round 10
// 93.547 us; speedup vs baseline: 1.3659x; 1.3659x over previous
//
#include <hip/hip_runtime.h>
#include <hip/hip_bf16.h>

#define BATCH 4096
#define NROWS 8192
#define DIM   128
#define NTILE 64
#define NSLOT 128   // 2 slots per col-block: (block*2 + wave-half)

typedef __bf16 bf16x8 __attribute__((ext_vector_type(8)));
typedef __bf16 bf16x2 __attribute__((ext_vector_type(2)));
typedef float  f32x4  __attribute__((ext_vector_type(4)));

typedef const __attribute__((address_space(1))) unsigned int* gptr_t;
typedef __attribute__((address_space(3))) unsigned int* lptr_t;

// ---------------------------------------------------------------------------
// Kernel 1: row-normalize z = concat(zx, zy) -> bf16 zn [8192 x 128].
// One wave per row. Zeroes out[0] (block 0). No other init needed: the Spart
// scheme below is race-free with full coverage (every cell written once).
// ---------------------------------------------------------------------------
__global__ __launch_bounds__(256) void normalize_kernel(
    const float* __restrict__ zx, const float* __restrict__ zy,
    ushort* __restrict__ zn, float* __restrict__ out)
{
  const int tid  = threadIdx.x;
  const int lane = tid & 63;
  const int w    = tid >> 6;
  const int row  = blockIdx.x * 4 + w;
  if (blockIdx.x == 0 && tid == 0) out[0] = 0.f;
  const float* src = (row < BATCH) ? (zx + (size_t)row * DIM)
                                   : (zy + (size_t)(row - BATCH) * DIM);
  float2 v = ((const float2*)src)[lane];
  float ss = v.x * v.x + v.y * v.y;
#pragma unroll
  for (int off = 1; off < 64; off <<= 1)
    ss += __shfl_xor(ss, off, 64);
  float inv = 1.0f / fmaxf(sqrtf(ss), 1e-8f);
  bf16x2 st;
  st.x = (__bf16)(v.x * inv);
  st.y = (__bf16)(v.y * inv);
  reinterpret_cast<bf16x2*>(zn + (size_t)row * DIM)[lane] = st;
}

// ---------------------------------------------------------------------------
// Kernel 2 (v9): pipelined symmetry-halved structure, ATOMIC-FREE, with
// PER-WAVE-HALF slots (fixes v8b's ln2 race: both wc-waves stored the same
// Spart cell, losing one column-half -> absmax 0.6875 = ln 2).
//
// Spart has 128 slots. Tile (rb,cb), wave (wr,wc):
//   row-side: partial sum over cols wc*64.. -> Spart[cb*2+wc][rb*128+rows]
//             (the two wc waves write DIFFERENT slots; rows disjoint by wr)
//   col-side: partial sum over rows wr*64.. -> Spart[rb*2+wr][cb*128+cols]
//             (the two wr waves write DIFFERENT slots; cols disjoint by wc;
//              skipped on diagonal tiles)
// Unique writer per (slot,row): for row-block t, slot c*2+h comes from tile
// (t,c) row-side if c<=t, else tile (c,t) col-side. finalize sums 128 slots.
//
// Decomposition (v5): lower triangle as 32 row-pairs {p, 63-p} of 65 tiles,
// 16 chunks each -> 512 blocks (2/CU); chunk 0: 5 tiles, rest 4. B tiles
// double-buffered in LDS (2x32 KiB): stage(t+1) -> compute(t) -> barrier.
// A-frags register-resident (<=1 reload at the row switch).
// launch_bounds(256,2): no spill (v7's (256,3) spilled ~35 MB -> 75 us).
// ---------------------------------------------------------------------------
__global__ __launch_bounds__(256, 2) void simloss_kernel(
    const ushort* __restrict__ zn, float* __restrict__ Spart,
    float* __restrict__ P)
{
  __shared__ ushort Bs[2][128 * 128];   // 2 x 32 KiB swizzled B tiles
  const int tid  = threadIdx.x;
  const int lane = tid & 63;
  const int w    = tid >> 6;
  const int wr   = w >> 1, wc = w & 1;
  const int q    = lane >> 4;     // quad 0..3
  const int l15  = lane & 15;

  const int p  = blockIdx.x >> 4;            // pair 0..31: rows {p, 63-p}
  const int ch = blockIdx.x & 15;            // chunk 0..15
  const int o0 = (ch == 0) ? 0 : 1 + ch * 4; // seq start: 0,5,9,...,61
  const int T  = (ch == 0) ? 5 : 4;          // tiles in this chunk
  const int L0 = p + 1;                      // tiles in short row (rb = p)

  // seq position o -> tile (rb, cb)
  auto tile_rc = [&](int o, int& rb, int& cb) {
    if (o < L0) { rb = p;      cb = o; }
    else        { rb = 63 - p; cb = o - L0; }
  };

  // Stage B tile for col-block cb into Bs[buf]. Chunk (row, c) -> LDS chunk
  // row*16 + (c ^ (row&15)); global_load_lds dest is uniform base + lane*16,
  // so the swizzle is applied on the per-lane GLOBAL source address.
  auto stage = [&](int cb, int buf) {
    const int C0 = cb * 128;
#pragma unroll
    for (int j = 0; j < 8; ++j) {
      const int Lbase = w * 512 + j * 64;          // uniform per wave
      const int row   = w * 32 + j * 4 + q;        // (Lbase+lane)>>4
      const int c     = l15 ^ (row & 15);
      const ushort* g = zn + (size_t)(C0 + row) * DIM + c * 8;
      __builtin_amdgcn_global_load_lds((gptr_t)g, (lptr_t)(&Bs[buf][Lbase * 8]),
                                       16, 0, 0);
    }
  };

  // A fragments: rows rb*128 + wr*64 + mi*16 + l15, k chunk q*8 within ks*32
  bf16x8 af[4][4];
  auto loadA = [&](int rb) {
    const int arow = rb * 128 + wr * 64 + l15;
#pragma unroll
    for (int mi = 0; mi < 4; ++mi)
#pragma unroll
      for (int ks = 0; ks < 4; ++ks) {
        const ushort* ap = zn + (size_t)(arow + mi * 16) * DIM + ks * 32 + q * 8;
        af[mi][ks] = *reinterpret_cast<const bf16x8*>(ap);
      }
  };

  int rb0, cb0;
  tile_rc(o0, rb0, cb0);
  stage(cb0, 0);       // prologue prefetch
  loadA(rb0);

  const float K1 = 2.8853900817779268f;  // (1/TEMP) * log2(e)

  __syncthreads();     // tile 0 staged (vmcnt(0) drained before s_barrier)

  for (int t = 0; t < T; ++t) {
    const int o = o0 + t;
    int trb, tcb;
    tile_rc(o, trb, tcb);
    int nrb = -1, ncb = -1;
    if (t + 1 < T) {
      tile_rc(o + 1, nrb, ncb);
      stage(ncb, (t & 1) ^ 1);   // prefetch next B into idle buffer
    }

    const ushort* bsc = &Bs[t & 1][0];

    f32x4 acc[4][4];
#pragma unroll
    for (int mi = 0; mi < 4; ++mi)
#pragma unroll
      for (int ni = 0; ni < 4; ++ni)
        acc[mi][ni] = (f32x4){0.f, 0.f, 0.f, 0.f};

#pragma unroll
    for (int ks = 0; ks < 4; ++ks) {
      bf16x8 bf[4];
#pragma unroll
      for (int ni = 0; ni < 4; ++ni) {
        const int nl  = wc * 64 + ni * 16 + l15;   // B row in tile (sim col)
        const int ck  = ks * 4 + q;                // k-chunk 0..15
        const int L   = nl * 16 + (ck ^ (nl & 15));
        bf[ni] = *reinterpret_cast<const bf16x8*>(bsc + L * 8);
      }
#pragma unroll
      for (int mi = 0; mi < 4; ++mi)
#pragma unroll
        for (int ni = 0; ni < 4; ++ni)
          acc[mi][ni] = __builtin_amdgcn_mfma_f32_16x16x32_bf16(
              af[mi][ks], bf[ni], acc[mi][ni], 0, 0, 0);
    }

    // Epilogue: v = exp(sim-2) = exp2(K1*dot - K1). Per-tile row & col sums.
    const bool diag = (trb == tcb);
    f32x4 Srow[4];
    float Scol[4];
#pragma unroll
    for (int mi = 0; mi < 4; ++mi) Srow[mi] = (f32x4){0.f, 0.f, 0.f, 0.f};
#pragma unroll
    for (int ni = 0; ni < 4; ++ni) Scol[ni] = 0.f;

#pragma unroll
    for (int mi = 0; mi < 4; ++mi)
#pragma unroll
      for (int ni = 0; ni < 4; ++ni) {
        f32x4 vv;
#pragma unroll
        for (int r = 0; r < 4; ++r) {
          float d = acc[mi][ni][r];
          float v = __builtin_amdgcn_exp2f(fmaf(d, K1, -K1));
          if (diag) {
            const int rl = wr * 64 + mi * 16 + q * 4 + r;
            const int cl = wc * 64 + ni * 16 + l15;
            if (rl == cl) v = 0.f;
          }
          vv[r] = v;
        }
        Srow[mi] += vv;
        Scol[ni] += (vv[0] + vv[1]) + (vv[2] + vv[3]);
      }

    // Positive pairs: tile (rb, rb-32) has sim[i, i-4096] at local rl==cl.
    if (trb - tcb == 32) {
#pragma unroll
      for (int mi = 0; mi < 4; ++mi) {
        const int rl0 = wr * 64 + mi * 16 + q * 4;
#pragma unroll
        for (int ni = 0; ni < 4; ++ni) {
          const int cl = wc * 64 + ni * 16 + l15;
#pragma unroll
          for (int r = 0; r < 4; ++r) {
            if (cl == rl0 + r) {
              const int gr = trb * 128 + rl0 + r;
              const float pv = 2.0f * acc[mi][ni][r];
              P[gr] = pv;
              P[gr - 4096] = pv;   // symmetric partner
            }
          }
        }
      }
    }

    // Row-side flush: reduce over l15 (this wave's 16-column group within its
    // wc-half); lane l15==0 stores one f32x4 per mi. Slot tcb*2+wc keeps the
    // two column-halves in SEPARATE slots -> no cross-wave race.
#pragma unroll
    for (int mi = 0; mi < 4; ++mi) {
      f32x4 v = Srow[mi];
#pragma unroll
      for (int r = 0; r < 4; ++r) {
        float s = v[r];
        s += __shfl_xor(s, 1, 64);
        s += __shfl_xor(s, 2, 64);
        s += __shfl_xor(s, 4, 64);
        s += __shfl_xor(s, 8, 64);
        v[r] = s;
      }
      if (l15 == 0)
        *reinterpret_cast<f32x4*>(
            &Spart[(size_t)(tcb * 2 + wc) * NROWS +
                   trb * 128 + wr * 64 + mi * 16 + q * 4]) = v;
    }

    // Col-side flush (non-diag): reduce over quads (rows of this wave's
    // wr-half); lanes q==0 store. Slot trb*2+wr separates the row-halves.
    if (!diag) {
#pragma unroll
      for (int ni = 0; ni < 4; ++ni) {
        float v = Scol[ni];
        v += __shfl_xor(v, 16, 64);
        v += __shfl_xor(v, 32, 64);
        if (lane < 16)
          Spart[(size_t)(trb * 2 + wr) * NROWS +
                tcb * 128 + wc * 64 + ni * 16 + l15] = v;
      }
    }

    if (t + 1 < T) {
      if (nrb != trb) loadA(nrb);  // one-time A reload at the row switch
      __syncthreads();             // stage(t+1) drained + WAR on Bs[t&1]
    }
  }
}

// ---------------------------------------------------------------------------
// Kernel 3: loss = mean_i( 2 + log(sum_{s<128} Spart[s][i]) - P_i )
// ---------------------------------------------------------------------------
__global__ __launch_bounds__(256) void finalize_kernel(
    const float* __restrict__ Spart, const float* __restrict__ P,
    float* __restrict__ out)
{
  const int i = blockIdx.x * 256 + threadIdx.x;
  float s = 0.f;
#pragma unroll 8
  for (int k = 0; k < NSLOT; ++k) s += Spart[(size_t)k * NROWS + i];
  float c = 2.0f + logf(s) - P[i];
#pragma unroll
  for (int off = 1; off < 64; off <<= 1)
    c += __shfl_xor(c, off, 64);
  __shared__ float wsum[4];
  const int lane = threadIdx.x & 63, w = threadIdx.x >> 6;
  if (lane == 0) wsum[w] = c;
  __syncthreads();
  if (threadIdx.x == 0)
    atomicAdd(out, (wsum[0] + wsum[1] + wsum[2] + wsum[3]) * (1.0f / NROWS));
}

// ---------------------------------------------------------------------------
extern "C" void kernel_launch(void* const* d_in, const int* in_sizes, int n_in,
                              void* d_out, int out_size, void* d_ws, size_t ws_size,
                              hipStream_t stream)
{
  const float* zx = (const float*)d_in[0];
  const float* zy = (const float*)d_in[1];
  ushort* zn = (ushort*)d_ws;                                      // 2 MiB bf16
  float*  P  = (float*)((char*)d_ws + (size_t)NROWS * DIM * 2);    // 32 KiB
  float*  Sp = P + NROWS;                                          // 4 MiB
  float*  out = (float*)d_out;

  normalize_kernel<<<NROWS / 4, 256, 0, stream>>>(zx, zy, zn, out);
  simloss_kernel<<<512, 256, 0, stream>>>(zn, Sp, P);
  finalize_kernel<<<NROWS / 256, 256, 0, stream>>>(Sp, P, out);
}

// Round 11
// 85.629 us; speedup vs baseline: 1.4922x; 1.0925x over previous
//
#include <hip/hip_runtime.h>
#include <hip/hip_bf16.h>

#define BATCH 4096
#define NROWS 8192
#define DIM   128
#define NTILE 64

typedef __bf16 bf16x8 __attribute__((ext_vector_type(8)));
typedef __bf16 bf16x2 __attribute__((ext_vector_type(2)));
typedef float  f32x4  __attribute__((ext_vector_type(4)));

typedef const __attribute__((address_space(1))) unsigned int* gptr_t;
typedef __attribute__((address_space(3))) unsigned int* lptr_t;

// ---------------------------------------------------------------------------
// Kernel 1: row-normalize z = concat(zx, zy) -> bf16 zn [8192 x 128].
// One wave per row. Zeroes S (blocks 0..31) and out (block 0) so later
// dispatches accumulate into poisoned workspace with no memset dispatches.
// ---------------------------------------------------------------------------
__global__ __launch_bounds__(256) void normalize_kernel(
    const float* __restrict__ zx, const float* __restrict__ zy,
    ushort* __restrict__ zn, float* __restrict__ S, float* __restrict__ out)
{
  const int tid  = threadIdx.x;
  const int lane = tid & 63;
  const int w    = tid >> 6;
  const int row  = blockIdx.x * 4 + w;
  if (blockIdx.x < 32) S[blockIdx.x * 256 + tid] = 0.f;
  if (blockIdx.x == 0 && tid == 0) out[0] = 0.f;
  const float* src = (row < BATCH) ? (zx + (size_t)row * DIM)
                                   : (zy + (size_t)(row - BATCH) * DIM);
  float2 v = ((const float2*)src)[lane];
  float ss = v.x * v.x + v.y * v.y;
#pragma unroll
  for (int off = 1; off < 64; off <<= 1)
    ss += __shfl_xor(ss, off, 64);
  float inv = 1.0f / fmaxf(sqrtf(ss), 1e-8f);
  bf16x2 st;
  st.x = (__bf16)(v.x * inv);
  st.y = (__bf16)(v.y * inv);
  reinterpret_cast<bf16x2*>(zn + (size_t)row * DIM)[lane] = st;
}

// ---------------------------------------------------------------------------
// Kernel 2 (v10): v5's pipelined symmetry-halved structure at 8 WAVES/BLOCK.
// v6's direct counters (MfmaUtil 5%, VALU 10%, HBM 3%, 0 conflicts) showed
// pure latency stall; v9 falsified the atomic theory (atomic-free was
// SLOWER). Remaining theory: TLP starvation — 2 waves/SIMD can't hide the
// per-tile dep chains (ds_read ~120cy, shfl-reduce ~100cy each, barrier).
// v10 doubles TLP: 512-thread blocks (8 waves, 4x2 wave grid), per-wave
// footprint halved (af[2][4], acc[2][4] -> ~115 VGPR, fits 128-cap of
// launch_bounds(512,4) = 2 blocks/CU = 16 waves/CU = 4/SIMD, no spill).
//
// Decomposition (v5): lower triangle as 32 row-pairs {p,63-p} of 65 tiles,
// 16 chunks -> 512 blocks; chunk 0: 5 tiles, rest 4 (<=1 A-reload/block).
// B tiles double-buffered in LDS (2x32 KiB): stage(t+1)->compute(t)->barrier.
// Row/col sums -> S[8192] via shfl-reduce + atomicAdd (S pre-zeroed; proven
// fastest in v5 vs v9's plain-store slots). Positive-pair tiles (rb-cb==32)
// write P[i] and mirror P[i-4096].
// ---------------------------------------------------------------------------
__global__ __launch_bounds__(512, 4) void simloss_kernel(
    const ushort* __restrict__ zn, float* __restrict__ S,
    float* __restrict__ P)
{
  __shared__ ushort Bs[2][128 * 128];   // 2 x 32 KiB swizzled B tiles
  const int tid  = threadIdx.x;
  const int lane = tid & 63;
  const int w    = tid >> 6;       // wave 0..7
  const int wr   = w >> 1;         // 0..3: 32-row band
  const int wc   = w & 1;          // 0..1: 64-col half
  const int q    = lane >> 4;      // quad 0..3
  const int l15  = lane & 15;

  const int p  = blockIdx.x >> 4;            // pair 0..31: rows {p, 63-p}
  const int ch = blockIdx.x & 15;            // chunk 0..15
  const int o0 = (ch == 0) ? 0 : 1 + ch * 4; // seq start: 0,5,9,...,61
  const int T  = (ch == 0) ? 5 : 4;          // tiles in this chunk
  const int L0 = p + 1;                      // tiles in short row (rb = p)

  auto tile_rc = [&](int o, int& rb, int& cb) {
    if (o < L0) { rb = p;      cb = o; }
    else        { rb = 63 - p; cb = o - L0; }
  };

  // Stage B tile for col-block cb into Bs[buf]. 8 waves x 4 iters x 64 lanes
  // = 2048 16B-chunks = 128 rows x 16 chunks. Chunk (row,c) -> LDS chunk
  // row*16 + (c ^ (row&15)); dest is uniform base + lane*16, so the swizzle
  // is applied on the per-lane GLOBAL source address.
  auto stage = [&](int cb, int buf) {
    const int C0 = cb * 128;
#pragma unroll
    for (int j = 0; j < 4; ++j) {
      const int Lbase = w * 256 + j * 64;          // uniform per wave
      const int row   = w * 16 + j * 4 + q;        // (Lbase+lane)>>4
      const int c     = l15 ^ (row & 15);
      const ushort* g = zn + (size_t)(C0 + row) * DIM + c * 8;
      __builtin_amdgcn_global_load_lds((gptr_t)g, (lptr_t)(&Bs[buf][Lbase * 8]),
                                       16, 0, 0);
    }
  };

  // A fragments: rows rb*128 + wr*32 + mi*16 + l15 (mi 0..1), k = ks*32+q*8+j
  bf16x8 af[2][4];
  auto loadA = [&](int rb) {
    const int arow = rb * 128 + wr * 32 + l15;
#pragma unroll
    for (int mi = 0; mi < 2; ++mi)
#pragma unroll
      for (int ks = 0; ks < 4; ++ks) {
        const ushort* ap = zn + (size_t)(arow + mi * 16) * DIM + ks * 32 + q * 8;
        af[mi][ks] = *reinterpret_cast<const bf16x8*>(ap);
      }
  };

  int rb0, cb0;
  tile_rc(o0, rb0, cb0);
  stage(cb0, 0);       // prologue prefetch
  loadA(rb0);

  f32x4 Srow[2];       // per mi, elems r=0..3, accumulated across the row run
#pragma unroll
  for (int mi = 0; mi < 2; ++mi) Srow[mi] = (f32x4){0.f, 0.f, 0.f, 0.f};

  const float K1 = 2.8853900817779268f;  // (1/TEMP) * log2(e)

  __syncthreads();     // tile 0 staged (vmcnt(0) drained before s_barrier)

  for (int t = 0; t < T; ++t) {
    const int o = o0 + t;
    int trb, tcb;
    tile_rc(o, trb, tcb);
    int nrb = -1, ncb = -1;
    if (t + 1 < T) {
      tile_rc(o + 1, nrb, ncb);
      stage(ncb, (t & 1) ^ 1);   // prefetch next B into idle buffer
    }

    const ushort* bsc = &Bs[t & 1][0];

    f32x4 acc[2][4];
#pragma unroll
    for (int mi = 0; mi < 2; ++mi)
#pragma unroll
      for (int ni = 0; ni < 4; ++ni)
        acc[mi][ni] = (f32x4){0.f, 0.f, 0.f, 0.f};

#pragma unroll
    for (int ks = 0; ks < 4; ++ks) {
      bf16x8 bf[4];
#pragma unroll
      for (int ni = 0; ni < 4; ++ni) {
        const int nl  = wc * 64 + ni * 16 + l15;   // B row in tile (sim col)
        const int ck  = ks * 4 + q;                // k-chunk 0..15
        const int L   = nl * 16 + (ck ^ (nl & 15));
        bf[ni] = *reinterpret_cast<const bf16x8*>(bsc + L * 8);
      }
#pragma unroll
      for (int mi = 0; mi < 2; ++mi)
#pragma unroll
        for (int ni = 0; ni < 4; ++ni)
          acc[mi][ni] = __builtin_amdgcn_mfma_f32_16x16x32_bf16(
              af[mi][ks], bf[ni], acc[mi][ni], 0, 0, 0);
    }

    // Epilogue: v = exp(sim-2) = exp2(K1*dot - K1). 32 exp2/wave/tile.
    const bool diag = (trb == tcb);
    float Scol[4];
#pragma unroll
    for (int ni = 0; ni < 4; ++ni) Scol[ni] = 0.f;

#pragma unroll
    for (int mi = 0; mi < 2; ++mi)
#pragma unroll
      for (int ni = 0; ni < 4; ++ni) {
        f32x4 vv;
#pragma unroll
        for (int r = 0; r < 4; ++r) {
          float d = acc[mi][ni][r];
          float v = __builtin_amdgcn_exp2f(fmaf(d, K1, -K1));
          if (diag) {
            const int rl = wr * 32 + mi * 16 + q * 4 + r;
            const int cl = wc * 64 + ni * 16 + l15;
            if (rl == cl) v = 0.f;
          }
          vv[r] = v;
        }
        Srow[mi] += vv;
        Scol[ni] += (vv[0] + vv[1]) + (vv[2] + vv[3]);
      }

    // Positive pairs: tile (rb, rb-32) has sim[i, i-4096] at local rl==cl.
    if (trb - tcb == 32) {
#pragma unroll
      for (int mi = 0; mi < 2; ++mi) {
        const int rl0 = wr * 32 + mi * 16 + q * 4;
#pragma unroll
        for (int ni = 0; ni < 4; ++ni) {
          const int cl = wc * 64 + ni * 16 + l15;
#pragma unroll
          for (int r = 0; r < 4; ++r) {
            if (cl == rl0 + r) {
              const int gr = trb * 128 + rl0 + r;
              const float pv = 2.0f * acc[mi][ni][r];
              P[gr] = pv;
              P[gr - 4096] = pv;   // symmetric partner
            }
          }
        }
      }
    }

    // Col-side flush (non-diag): reduce over quads (the wave's 32 rows);
    // lanes q==0 atomicAdd; the 4 wr-waves of each wc-half combine via S.
    if (!diag) {
#pragma unroll
      for (int ni = 0; ni < 4; ++ni) {
        float v = Scol[ni];
        v += __shfl_xor(v, 16, 64);
        v += __shfl_xor(v, 32, 64);
        if (lane < 16)
          atomicAdd(&S[tcb * 128 + wc * 64 + ni * 16 + l15], v);
      }
    }

    // Row-side flush at row switch or block end; the 2 wc-waves combine via S.
    const bool flushR = (t == T - 1) || (nrb != trb);
    if (flushR) {
#pragma unroll
      for (int mi = 0; mi < 2; ++mi)
#pragma unroll
        for (int r = 0; r < 4; ++r) {
          float v = Srow[mi][r];
          v += __shfl_xor(v, 1, 64);
          v += __shfl_xor(v, 2, 64);
          v += __shfl_xor(v, 4, 64);
          v += __shfl_xor(v, 8, 64);
          if (l15 == 0)
            atomicAdd(&S[trb * 128 + wr * 32 + mi * 16 + q * 4 + r], v);
        }
#pragma unroll
      for (int mi = 0; mi < 2; ++mi) Srow[mi] = (f32x4){0.f, 0.f, 0.f, 0.f};
    }

    if (t + 1 < T) {
      if (nrb != trb) loadA(nrb);  // one-time A reload at the row switch
      __syncthreads();             // stage(t+1) drained + WAR on Bs[t&1]
    }
  }
}

// ---------------------------------------------------------------------------
// Kernel 3: loss = mean_i( 2 + log(S_i) - P_i ); out zeroed by normalize.
// ---------------------------------------------------------------------------
__global__ __launch_bounds__(256) void finalize_kernel(
    const float* __restrict__ S, const float* __restrict__ P,
    float* __restrict__ out)
{
  const int i = blockIdx.x * 256 + threadIdx.x;
  float c = 2.0f + logf(S[i]) - P[i];
#pragma unroll
  for (int off = 1; off < 64; off <<= 1)
    c += __shfl_xor(c, off, 64);
  __shared__ float wsum[4];
  const int lane = threadIdx.x & 63, w = threadIdx.x >> 6;
  if (lane == 0) wsum[w] = c;
  __syncthreads();
  if (threadIdx.x == 0)
    atomicAdd(out, (wsum[0] + wsum[1] + wsum[2] + wsum[3]) * (1.0f / NROWS));
}

// ---------------------------------------------------------------------------
extern "C" void kernel_launch(void* const* d_in, const int* in_sizes, int n_in,
                              void* d_out, int out_size, void* d_ws, size_t ws_size,
                              hipStream_t stream)
{
  const float* zx = (const float*)d_in[0];
  const float* zy = (const float*)d_in[1];
  ushort* zn = (ushort*)d_ws;                                      // 2 MiB bf16
  float*  P  = (float*)((char*)d_ws + (size_t)NROWS * DIM * 2);    // 32 KiB
  float*  S  = P + NROWS;                                          // 32 KiB
  float*  out = (float*)d_out;

  normalize_kernel<<<NROWS / 4, 256, 0, stream>>>(zx, zy, zn, S, out);
  simloss_kernel<<<512, 512, 0, stream>>>(zn, S, P);
  finalize_kernel<<<NROWS / 256, 256, 0, stream>>>(S, P, out);
}